// Round 6
// baseline (253.873 us; speedup 1.0000x reference)
//
#include <hip/hip_runtime.h>
#include <math.h>

typedef _Float16 half8_t __attribute__((ext_vector_type(8)));
typedef _Float16 half4_t __attribute__((ext_vector_type(4)));
typedef float f32x4 __attribute__((ext_vector_type(4)));

#define MFMA16(a, b, c) __builtin_amdgcn_mfma_f32_16x16x32_f16((a), (b), (c), 0, 0, 0)

// log2(e) / sqrt(128): fold softmax scale AND exp->exp2 conversion into q.
#define SCALE_Q (0.08838834764831845f * 1.44269504088896340736f)

// ---------------------------------------------------------------------------
// Kernel 0: W [512][128] fp32  ->  Wt [128][512] fp16   (x3 for q,k,v)
// ---------------------------------------------------------------------------
__global__ __launch_bounds__(256) void wt_kernel(const float* __restrict__ Wq,
                                                 const float* __restrict__ Wk,
                                                 const float* __restrict__ Wv,
                                                 _Float16* __restrict__ WtAll) {
    int y = blockIdx.y;
    const float* W = (y == 0) ? Wq : (y == 1) ? Wk : Wv;
    int idx = blockIdx.x * 256 + threadIdx.x;
    int kk = idx >> 7;
    int d  = idx & 127;
    WtAll[y * 65536 + d * 512 + kk] = (_Float16)W[idx];
}

// ---------------------------------------------------------------------------
// Kernel 1: projection GEMM, BARRIER-FREE / NO-LDS.
// Each wave: 16 rows x 128 cols, K=512 in 16 steps. A fp32 direct from HBM
// (register prefetch), W fragments direct from L2. 768 blocks = 3072 waves.
// ---------------------------------------------------------------------------
__global__ __launch_bounds__(256, 4) void proj_kernel(
    const float* __restrict__ q_in, const float* __restrict__ k_in,
    const float* __restrict__ v_in, const _Float16* __restrict__ WtAll,
    const float* __restrict__ biasq, const float* __restrict__ biask,
    const float* __restrict__ biasv,
    _Float16* __restrict__ qbuf, _Float16* __restrict__ kbuf,
    _Float16* __restrict__ vbuf) {
    int bid = blockIdx.x;
    int y = bid >> 8;          // 0..2 : q,k,v
    int g = bid & 255;         // 0..255
    int tid = threadIdx.x, w = tid >> 6, lane = tid & 63;
    int quad = lane >> 4, l16 = lane & 15;

    const float* x = (y == 0) ? q_in : (y == 1) ? k_in : v_in;
    const _Float16* Wt = WtAll + y * 65536;
    const float* bias = (y == 0) ? biasq : (y == 1) ? biask : biasv;

    int row = g * 64 + w * 16 + l16;     // A row for this lane (m = l16)
    const float* ap = x + (size_t)row * 512 + quad * 8;
    const _Float16* wp = Wt + (size_t)l16 * 512 + quad * 8;

    f32x4 acc[8] = {};
    float4 a0 = ((const float4*)ap)[0];
    float4 a1 = ((const float4*)(ap + 4))[0];

    for (int kb = 0; kb < 512; kb += 32) {
        half8_t bf[8];
#pragma unroll
        for (int nt = 0; nt < 8; nt++)
            bf[nt] = *(const half8_t*)(wp + (size_t)nt * 8192 + kb);
        half8_t af;
        af[0] = (_Float16)a0.x; af[1] = (_Float16)a0.y;
        af[2] = (_Float16)a0.z; af[3] = (_Float16)a0.w;
        af[4] = (_Float16)a1.x; af[5] = (_Float16)a1.y;
        af[6] = (_Float16)a1.z; af[7] = (_Float16)a1.w;
        if (kb + 32 < 512) {   // prefetch next A chunk (HBM stream)
            a0 = ((const float4*)(ap + kb + 32))[0];
            a1 = ((const float4*)(ap + kb + 36))[0];
        }
#pragma unroll
        for (int nt = 0; nt < 8; nt++)
            acc[nt] = MFMA16(af, bf[nt], acc[nt]);
    }

    float scale = (y == 0) ? SCALE_Q : 1.0f;
    _Float16* dst = (y == 0) ? qbuf : (y == 1) ? kbuf : vbuf;
    int orow = g * 64 + w * 16 + quad * 4;    // C/D row = quad*4+r
#pragma unroll
    for (int nt = 0; nt < 8; nt++) {
        int d = nt * 16 + l16;
        float b = bias[d];
#pragma unroll
        for (int r = 0; r < 4; r++)
            dst[(size_t)(orow + r) * 128 + d] =
                (_Float16)((acc[nt][r] + b) * scale);
    }
}

// ---------------------------------------------------------------------------
// Kernel 1b: transpose v [8][2048][128] -> vt [8][128][2048].  512 blocks.
// ---------------------------------------------------------------------------
__global__ __launch_bounds__(256) void vt_kernel(const _Float16* __restrict__ vbuf,
                                                 _Float16* __restrict__ vtbuf) {
    __shared__ _Float16 t[64 * 72];
    int bb = blockIdx.x >> 6;
    int st = (blockIdx.x >> 1) & 31;   // s tile (64)
    int dt = blockIdx.x & 1;           // d tile (64)
    int tid = threadIdx.x;
    int r = tid >> 2, c = (tid & 3) * 16;
    const _Float16* src =
        vbuf + ((size_t)bb * 2048 + st * 64 + r) * 128 + dt * 64 + c;
    *(half8_t*)&t[r * 72 + c]     = *(const half8_t*)src;
    *(half8_t*)&t[r * 72 + c + 8] = *(const half8_t*)(src + 8);
    __syncthreads();
    int dr = tid >> 2, sc = (tid & 3) * 16;
    _Float16* dstp =
        vtbuf + ((size_t)bb * 128 + dt * 64 + dr) * 2048 + st * 64 + sc;
    half8_t o0, o1;
#pragma unroll
    for (int i = 0; i < 8; i++) {
        o0[i] = t[(sc + i) * 72 + dr];
        o1[i] = t[(sc + 8 + i) * 72 + dr];
    }
    *(half8_t*)dstp       = o0;
    *(half8_t*)(dstp + 8) = o1;
}

// ---------------------------------------------------------------------------
// Kernel 2: flash attention, BARRIER-FREE.  512 blocks x 4 independent waves.
// Each wave: 32 q (two 16-q halves) x 512 keys (kv-split 4).  K and V
// fragments direct from L2; only the P round-trip uses (per-wave) LDS.
// ---------------------------------------------------------------------------
__global__ __launch_bounds__(256, 2) void attn_kernel(
    const _Float16* __restrict__ qbuf, const _Float16* __restrict__ kbuf,
    const _Float16* __restrict__ vtbuf, _Float16* __restrict__ o_part,
    float2* __restrict__ ml) {
    int bid = blockIdx.x;          // 0..511
    int sp = bid >> 7;             // kv split 0..3
    int g  = bid & 127;            // q-block (128 rows each)
    int tid = threadIdx.x, w = tid >> 6, lane = tid & 63;
    int quad = lane >> 4, l16 = lane & 15;
    int rowbase = g * 128 + w * 32;
    int bb = rowbase >> 11;
    int q0 = rowbase & 2047;
    int kv0 = sp * 512;

    __shared__ _Float16 smem[18432];     // 36 KB: 4 waves x 4608
    _Float16* Pt = smem + w * 4608;      // per-wave [2][16][72]; epi scratch

    const _Float16* kbp = kbuf + ((size_t)bb * 2048 + kv0) * 128 + quad * 8;
    const _Float16* vbp = vtbuf + (size_t)bb * 262144 + kv0 + quad * 8;
    const _Float16* qp  = qbuf + ((size_t)bb * 2048 + q0) * 128 + quad * 8;

    // persistent Q fragments (B operand: n=l16, k=quad*8+j)
    half8_t qf0[4], qf1[4];
#pragma unroll
    for (int kc = 0; kc < 4; kc++) {
        qf0[kc] = *(const half8_t*)(qp + (size_t)l16 * 128 + kc * 32);
        qf1[kc] = *(const half8_t*)(qp + (size_t)(16 + l16) * 128 + kc * 32);
    }

    f32x4 o0[8] = {}, o1[8] = {};
    float m0 = -INFINITY, l0 = 0.f, m1 = -INFINITY, l1 = 0.f;

    for (int kv = 0; kv < 512; kv += 64) {
        // S^T = K Q^T for both q-halves (K frags direct from L2)
        f32x4 s0[4] = {}, s1[4] = {};
#pragma unroll
        for (int kc = 0; kc < 4; kc++) {
            half8_t kf[4];
            const _Float16* kp = kbp + (size_t)kv * 128 + kc * 32;
#pragma unroll
            for (int kt = 0; kt < 4; kt++)
                kf[kt] = *(const half8_t*)(kp + (size_t)(kt * 16 + l16) * 128);
#pragma unroll
            for (int kt = 0; kt < 4; kt++) {
                s0[kt] = MFMA16(kf[kt], qf0[kc], s0[kt]);
                s1[kt] = MFMA16(kf[kt], qf1[kc], s1[kt]);
            }
        }
        // V fragments (independent of K results; latency covered by softmax)
        half8_t vv0[8], vv1[8];
#pragma unroll
        for (int dt = 0; dt < 8; dt++) {
            const _Float16* vp = vbp + (size_t)(dt * 16 + l16) * 2048 + kv;
            vv0[dt] = *(const half8_t*)vp;
            vv1[dt] = *(const half8_t*)(vp + 32);
        }
        // ---- half 0: softmax + PV
        {
            float mx = m0;
#pragma unroll
            for (int kt = 0; kt < 4; kt++)
#pragma unroll
                for (int r = 0; r < 4; r++) mx = fmaxf(mx, s0[kt][r]);
            mx = fmaxf(mx, __shfl_xor(mx, 16, 64));
            mx = fmaxf(mx, __shfl_xor(mx, 32, 64));
            float alpha = exp2f(m0 - mx);
            float rs = 0.f;
#pragma unroll
            for (int kt = 0; kt < 4; kt++) {
                half4_t pk;
#pragma unroll
                for (int r = 0; r < 4; r++) {
                    float p = exp2f(s0[kt][r] - mx);
                    rs += p;
                    pk[r] = (_Float16)p;
                }
                *(half4_t*)&Pt[l16 * 72 + kt * 16 + quad * 4] = pk;
            }
            rs += __shfl_xor(rs, 16, 64);
            rs += __shfl_xor(rs, 32, 64);
            l0 = l0 * alpha + rs;
            m0 = mx;
            float ar0 = __shfl(alpha, quad * 4 + 0, 64);
            float ar1 = __shfl(alpha, quad * 4 + 1, 64);
            float ar2 = __shfl(alpha, quad * 4 + 2, 64);
            float ar3 = __shfl(alpha, quad * 4 + 3, 64);
#pragma unroll
            for (int dt = 0; dt < 8; dt++) {
                o0[dt][0] *= ar0; o0[dt][1] *= ar1;
                o0[dt][2] *= ar2; o0[dt][3] *= ar3;
            }
            half8_t pa0 = *(const half8_t*)&Pt[l16 * 72 + quad * 8];
            half8_t pa1 = *(const half8_t*)&Pt[l16 * 72 + 32 + quad * 8];
#pragma unroll
            for (int dt = 0; dt < 8; dt++) {
                o0[dt] = MFMA16(pa0, vv0[dt], o0[dt]);
                o0[dt] = MFMA16(pa1, vv1[dt], o0[dt]);
            }
        }
        // ---- half 1: softmax + PV
        {
            _Float16* Pt1 = Pt + 1152;
            float mx = m1;
#pragma unroll
            for (int kt = 0; kt < 4; kt++)
#pragma unroll
                for (int r = 0; r < 4; r++) mx = fmaxf(mx, s1[kt][r]);
            mx = fmaxf(mx, __shfl_xor(mx, 16, 64));
            mx = fmaxf(mx, __shfl_xor(mx, 32, 64));
            float alpha = exp2f(m1 - mx);
            float rs = 0.f;
#pragma unroll
            for (int kt = 0; kt < 4; kt++) {
                half4_t pk;
#pragma unroll
                for (int r = 0; r < 4; r++) {
                    float p = exp2f(s1[kt][r] - mx);
                    rs += p;
                    pk[r] = (_Float16)p;
                }
                *(half4_t*)&Pt1[l16 * 72 + kt * 16 + quad * 4] = pk;
            }
            rs += __shfl_xor(rs, 16, 64);
            rs += __shfl_xor(rs, 32, 64);
            l1 = l1 * alpha + rs;
            m1 = mx;
            float ar0 = __shfl(alpha, quad * 4 + 0, 64);
            float ar1 = __shfl(alpha, quad * 4 + 1, 64);
            float ar2 = __shfl(alpha, quad * 4 + 2, 64);
            float ar3 = __shfl(alpha, quad * 4 + 3, 64);
#pragma unroll
            for (int dt = 0; dt < 8; dt++) {
                o1[dt][0] *= ar0; o1[dt][1] *= ar1;
                o1[dt][2] *= ar2; o1[dt][3] *= ar3;
            }
            half8_t pa0 = *(const half8_t*)&Pt1[l16 * 72 + quad * 8];
            half8_t pa1 = *(const half8_t*)&Pt1[l16 * 72 + 32 + quad * 8];
#pragma unroll
            for (int dt = 0; dt < 8; dt++) {
                o1[dt] = MFMA16(pa0, vv0[dt], o1[dt]);
                o1[dt] = MFMA16(pa1, vv1[dt], o1[dt]);
            }
        }
    }

    // epilogue: normalized fp16 partial via per-wave LDS, plus (m,l)
    size_t orow_g = (size_t)sp * 16384 + (size_t)bb * 2048 + q0;
    {
        float li0 = 1.f / __shfl(l0, quad * 4 + 0, 64);
        float li1 = 1.f / __shfl(l0, quad * 4 + 1, 64);
        float li2 = 1.f / __shfl(l0, quad * 4 + 2, 64);
        float li3 = 1.f / __shfl(l0, quad * 4 + 3, 64);
#pragma unroll
        for (int dt = 0; dt < 8; dt++) {
            int base = (quad * 4) * 136 + dt * 16 + l16;
            Pt[base]       = (_Float16)(o0[dt][0] * li0);
            Pt[base + 136] = (_Float16)(o0[dt][1] * li1);
            Pt[base + 272] = (_Float16)(o0[dt][2] * li2);
            Pt[base + 408] = (_Float16)(o0[dt][3] * li3);
        }
        if (lane < 16) ml[orow_g + lane] = make_float2(m0, l0);
        int rr = lane >> 2, cc = (lane & 3) * 32;
        _Float16* op = o_part + (orow_g + rr) * 128 + cc;
#pragma unroll
        for (int i = 0; i < 4; i++)
            *(half8_t*)(op + i * 8) = *(const half8_t*)&Pt[rr * 136 + cc + i * 8];
    }
    {
        float li0 = 1.f / __shfl(l1, quad * 4 + 0, 64);
        float li1 = 1.f / __shfl(l1, quad * 4 + 1, 64);
        float li2 = 1.f / __shfl(l1, quad * 4 + 2, 64);
        float li3 = 1.f / __shfl(l1, quad * 4 + 3, 64);
#pragma unroll
        for (int dt = 0; dt < 8; dt++) {
            int base = (quad * 4) * 136 + dt * 16 + l16;
            Pt[base]       = (_Float16)(o1[dt][0] * li0);
            Pt[base + 136] = (_Float16)(o1[dt][1] * li1);
            Pt[base + 272] = (_Float16)(o1[dt][2] * li2);
            Pt[base + 408] = (_Float16)(o1[dt][3] * li3);
        }
        if (lane < 16) ml[orow_g + 16 + lane] = make_float2(m1, l1);
        int rr = lane >> 2, cc = (lane & 3) * 32;
        _Float16* op = o_part + (orow_g + 16 + rr) * 128 + cc;
#pragma unroll
        for (int i = 0; i < 4; i++)
            *(half8_t*)(op + i * 8) = *(const half8_t*)&Pt[rr * 136 + cc + i * 8];
    }
}

// ---------------------------------------------------------------------------
// Kernel 3: combine 4 split-KV partials.  1024 blocks x 256 thr.
// ---------------------------------------------------------------------------
__global__ __launch_bounds__(256) void comb_kernel(
    const _Float16* __restrict__ o_part, const float2* __restrict__ ml,
    float* __restrict__ out) {
    int tid = threadIdx.x;
    int row = blockIdx.x * 16 + (tid >> 4);
    int d0 = (tid & 15) * 8;

    float2 s0 = ml[row];
    float2 s1 = ml[16384 + row];
    float2 s2 = ml[32768 + row];
    float2 s3 = ml[49152 + row];
    float M = fmaxf(fmaxf(s0.x, s1.x), fmaxf(s2.x, s3.x));
    float w0 = s0.y * exp2f(s0.x - M);
    float w1 = s1.y * exp2f(s1.x - M);
    float w2 = s2.y * exp2f(s2.x - M);
    float w3 = s3.y * exp2f(s3.x - M);
    float inv = 1.0f / (w0 + w1 + w2 + w3);
    w0 *= inv; w1 *= inv; w2 *= inv; w3 *= inv;

    size_t base = (size_t)row * 128 + d0;
    half8_t h0 = *(const half8_t*)&o_part[base];
    half8_t h1 = *(const half8_t*)&o_part[(size_t)16384 * 128 + base];
    half8_t h2 = *(const half8_t*)&o_part[(size_t)32768 * 128 + base];
    half8_t h3 = *(const half8_t*)&o_part[(size_t)49152 * 128 + base];

    float4 lo, hi;
    lo.x = w0 * (float)h0[0] + w1 * (float)h1[0] + w2 * (float)h2[0] + w3 * (float)h3[0];
    lo.y = w0 * (float)h0[1] + w1 * (float)h1[1] + w2 * (float)h2[1] + w3 * (float)h3[1];
    lo.z = w0 * (float)h0[2] + w1 * (float)h1[2] + w2 * (float)h2[2] + w3 * (float)h3[2];
    lo.w = w0 * (float)h0[3] + w1 * (float)h1[3] + w2 * (float)h2[3] + w3 * (float)h3[3];
    hi.x = w0 * (float)h0[4] + w1 * (float)h1[4] + w2 * (float)h2[4] + w3 * (float)h3[4];
    hi.y = w0 * (float)h0[5] + w1 * (float)h1[5] + w2 * (float)h2[5] + w3 * (float)h3[5];
    hi.z = w0 * (float)h0[6] + w1 * (float)h1[6] + w2 * (float)h2[6] + w3 * (float)h3[6];
    hi.w = w0 * (float)h0[7] + w1 * (float)h1[7] + w2 * (float)h2[7] + w3 * (float)h3[7];
    *(float4*)&out[base]     = lo;
    *(float4*)&out[base + 4] = hi;
}

// ---------------------------------------------------------------------------
extern "C" void kernel_launch(void* const* d_in, const int* in_sizes, int n_in,
                              void* d_out, int out_size, void* d_ws,
                              size_t ws_size, hipStream_t stream) {
    const float* q_in = (const float*)d_in[0];
    const float* k_in = (const float*)d_in[1];
    const float* v_in = (const float*)d_in[2];
    const float* Wq = (const float*)d_in[3];
    const float* Wk = (const float*)d_in[4];
    const float* Wv = (const float*)d_in[5];
    const float* bq = (const float*)d_in[6];
    const float* bk = (const float*)d_in[7];
    const float* bv = (const float*)d_in[8];
    float* out = (float*)d_out;

    char* ws = (char*)d_ws;
    _Float16* WtAll  = (_Float16*)ws;                    // 384 KB
    _Float16* qbuf   = (_Float16*)(ws + 393216);         // 4 MB
    _Float16* kbuf   = (_Float16*)(ws + 4587520);        // 4 MB
    _Float16* vtbuf  = (_Float16*)(ws + 8781824);        // 4 MB
    _Float16* o_part = (_Float16*)(ws + 12976128);       // 16 MB
    _Float16* vbuf   = o_part;                           // reuse: dead before attn
    float2*   ml     = (float2*)(ws + 29753344);         // 512 KB

    wt_kernel<<<dim3(256, 3), 256, 0, stream>>>(Wq, Wk, Wv, WtAll);
    proj_kernel<<<dim3(768), 256, 0, stream>>>(q_in, k_in, v_in, WtAll, bq,
                                               bk, bv, qbuf, kbuf, vbuf);
    vt_kernel<<<dim3(512), 256, 0, stream>>>(vbuf, vtbuf);
    attn_kernel<<<dim3(512), 256, 0, stream>>>(qbuf, kbuf, vtbuf, o_part, ml);
    comb_kernel<<<dim3(1024), 256, 0, stream>>>(o_part, ml, out);
}